// Round 3
// baseline (2018.044 us; speedup 1.0000x reference)
//
#include <hip/hip_runtime.h>
#include <cstdint>
#include <cstddef>

typedef __bf16 bf16_t;
typedef float f32x4 __attribute__((ext_vector_type(4)));
typedef __bf16 bf16x8 __attribute__((ext_vector_type(8)));

// async global->LDS, 16B per lane. LDS dest is wave-uniform base + lane*16B.
#define GLOAD_LDS16(gp, lp)                                                        \
    __builtin_amdgcn_global_load_lds(                                              \
        (const __attribute__((address_space(1))) void*)(gp),                       \
        (__attribute__((address_space(3))) void*)(lp), 16, 0, 0)

// =====================================================================
// GEMM: C[M,N] = A[M,K] @ BT[N,K]^T (+ bias[N]), bf16 in, OutT out, fp32 acc.
// N%128==0, K%64==0; M arbitrary (clamped loads, guarded stores).
// Block 256 thr = 4 waves (2x2), wave tile 64x64 via 4x4 mfma_16x16x32_bf16.
// LDS fragment-ordered: chunk c (1KB) = (kstep=c>>3, tile16=c&7); lane i in
// chunk holds row tile*16+(i&15), cols kstep*32+(i>>4)*8 -> frag read is
// contiguous base+lane*16B (conflict-free b128).
// T3-minimum 2-phase: double-buffered LDS, stage(t+1) issued BEFORE compute
// on buf[t&1]; ONE __syncthreads per K-step (drains vmcnt+lgkmcnt). The
// stage loads fly under the ds_read+MFMA phase instead of being drained
// immediately (the round-1/2 structure exposed ~900cy HBM latency per step).
// =====================================================================
template <typename OutT>
__global__ __launch_bounds__(256, 2)
void gemm_bt(const bf16_t* __restrict__ A, const bf16_t* __restrict__ BT,
             OutT* __restrict__ C, const float* __restrict__ bias,
             int M, int K, int ldA, int ldBT, int ldC)
{
    __shared__ __align__(16) bf16_t As[2][8192];   // 2 x 16 KB
    __shared__ __align__(16) bf16_t Bs[2][8192];   // 2 x 16 KB

    const int bn0 = blockIdx.x * 128;
    const int bm0 = blockIdx.y * 128;
    const int tid  = threadIdx.x;
    const int lane = tid & 63;
    const int w    = tid >> 6;          // wave 0..3
    const int wr   = w >> 1, wc = w & 1;
    const int lm   = lane & 15, lq = lane >> 4;

    f32x4 acc[4][4];
    #pragma unroll
    for (int i = 0; i < 4; i++)
        #pragma unroll
        for (int j = 0; j < 4; j++) acc[i][j] = (f32x4){0.f, 0.f, 0.f, 0.f};

    // Per-lane global base addresses for this wave's 4 chunks (A and B).
    // chunk c = w*4+ci: ks=c>>3, tile=c&7; lane i -> row tile*16+(i&15),
    // col ks*32+(i>>4)*8. LDS lands at &As[buf][c*512] + lane*16B.
    const bf16_t* aptr[4];
    const bf16_t* bptr[4];
    #pragma unroll
    for (int ci = 0; ci < 4; ci++) {
        const int c    = w * 4 + ci;
        const int ks   = c >> 3, tile = c & 7;
        const int col  = ks * 32 + lq * 8;
        int arow = bm0 + tile * 16 + lm;
        if (arow > M - 1) arow = M - 1;       // clamp: garbage compute, no OOB
        aptr[ci] = A  + (size_t)arow * ldA + col;
        bptr[ci] = BT + (size_t)(bn0 + tile * 16 + lm) * ldBT + col;
    }

    const int nt = K >> 6;                    // K-steps of 64

    // prologue: stage tile 0 -> buf 0
    #pragma unroll
    for (int ci = 0; ci < 4; ci++) {
        const int c = w * 4 + ci;
        GLOAD_LDS16(aptr[ci], &As[0][c * 512]);
        GLOAD_LDS16(bptr[ci], &Bs[0][c * 512]);
    }
    __syncthreads();                          // drains vmcnt(0): tile 0 ready

    for (int t = 0; t < nt; ++t) {
        const int cur = t & 1;
        // issue next-tile stage into the other buffer (read last iter,
        // all waves past the barrier -> safe to overwrite)
        if (t + 1 < nt) {
            const int k0 = (t + 1) << 6;
            #pragma unroll
            for (int ci = 0; ci < 4; ci++) {
                const int c = w * 4 + ci;
                GLOAD_LDS16(aptr[ci] + k0, &As[cur ^ 1][c * 512]);
                GLOAD_LDS16(bptr[ci] + k0, &Bs[cur ^ 1][c * 512]);
            }
        }
        // compute on current buffer while next-tile loads fly
        #pragma unroll
        for (int ks = 0; ks < 2; ks++) {
            bf16x8 af[4], bfr[4];
            #pragma unroll
            for (int t4 = 0; t4 < 4; t4++) {
                af[t4]  = *(const bf16x8*)&As[cur][(ks * 8 + wr * 4 + t4) * 512 + lane * 8];
                bfr[t4] = *(const bf16x8*)&Bs[cur][(ks * 8 + wc * 4 + t4) * 512 + lane * 8];
            }
            #pragma unroll
            for (int mt = 0; mt < 4; mt++)
                #pragma unroll
                for (int nt2 = 0; nt2 < 4; nt2++)
                    acc[mt][nt2] = __builtin_amdgcn_mfma_f32_16x16x32_bf16(
                        af[mt], bfr[nt2], acc[mt][nt2], 0, 0, 0);
        }
        __syncthreads();   // drains own vmcnt(0)+lgkmcnt(0); next tile ready
    }

    // epilogue: C/D layout col=lane&15, row=(lane>>4)*4+reg   [m89/m91]
    float bv[4];
    #pragma unroll
    for (int nt2 = 0; nt2 < 4; nt2++)
        bv[nt2] = bias ? bias[bn0 + wc * 64 + nt2 * 16 + lm] : 0.f;
    #pragma unroll
    for (int mt = 0; mt < 4; mt++)
        #pragma unroll
        for (int r2 = 0; r2 < 4; r2++) {
            const int row = bm0 + wr * 64 + mt * 16 + lq * 4 + r2;
            if (row >= M) continue;
            OutT* cp = C + (size_t)row * ldC + bn0 + wc * 64 + lm;
            #pragma unroll
            for (int nt2 = 0; nt2 < 4; nt2++)
                cp[nt2 * 16] = (OutT)(acc[mt][nt2][r2] + bv[nt2]);
        }
}

// =====================================================================
// Tiled transpose + cast: dst[n][k] = scale * src[k][n]; src SrcT, dst bf16.
// =====================================================================
template <typename SrcT>
__global__ void transpose_to_bf16(const SrcT* __restrict__ src, bf16_t* __restrict__ dst,
                                  int K, int N, int ldsrc, int lddst,
                                  const float* __restrict__ scale_ptr)
{
    __shared__ float tile[32][33];
    const int k0 = blockIdx.x * 32, n0 = blockIdx.y * 32;
    const int tx = threadIdx.x & 31, ty = threadIdx.x >> 5;   // 256 thr
    #pragma unroll
    for (int i = 0; i < 4; i++) {
        int k = k0 + ty + 8 * i;
        tile[ty + 8 * i][tx] = (k < K && n0 + tx < N)
            ? (float)src[(size_t)k * ldsrc + n0 + tx] : 0.f;
    }
    __syncthreads();
    const float s = scale_ptr ? *scale_ptr : 1.0f;
    #pragma unroll
    for (int i = 0; i < 4; i++) {
        int n = n0 + ty + 8 * i, k = k0 + tx;
        if (n < N && k < K)
            dst[(size_t)n * lddst + k] = (bf16_t)(s * tile[tx][ty + 8 * i]);
    }
}

// fp32 -> bf16 cast, n % 4 == 0
__global__ void cast_f32_bf16(const float* __restrict__ src, bf16_t* __restrict__ dst, long n)
{
    long i = ((long)blockIdx.x * blockDim.x + threadIdx.x) * 4;
    if (i >= n) return;
    const float4 v = *(const float4*)(src + i);
    bf16_t d0 = (bf16_t)v.x, d1 = (bf16_t)v.y, d2 = (bf16_t)v.z, d3 = (bf16_t)v.w;
    dst[i] = d0; dst[i + 1] = d1; dst[i + 2] = d2; dst[i + 3] = d3;
}

// ---- small prep kernels (all fp32 inputs) ----
__global__ void prep_biasA(const float* __restrict__ qkv_b, float* __restrict__ biasA) {
    int n = blockIdx.x * 256 + threadIdx.x;
    if (n < 3840) biasA[n] = (n < 3072) ? qkv_b[n] : 0.f;
}

__global__ void prep_biasO(const float* __restrict__ proj_b, const float* __restrict__ dp_b,
                           const float* __restrict__ proj_w, const float* __restrict__ dgamma,
                           float* __restrict__ biasO) {
    int n = blockIdx.x * 256 + threadIdx.x;
    if (n >= 1024) return;
    float acc = 0.f;
    for (int m = 0; m < 1024; m++) acc += dp_b[m] * proj_w[m * 1024 + n];
    biasO[n] = proj_b[n] + (*dgamma) * acc;
}

__global__ void prep_biasH(const float* __restrict__ rpb, const int* __restrict__ rel,
                           float* __restrict__ biasH) {
    int t = blockIdx.x * 256 + threadIdx.x;     // t = ij*32 + h
    if (t >= 32 * 49 * 49) return;
    int h = t & 31, ij = t >> 5;
    biasH[(size_t)h * 2401 + ij] = rpb[(size_t)rel[ij] * 32 + h];
}

// =====================================================================
// Attention: one 64-thread block per (window wb, head h).
// QKVL row (3840): [q|k|v] at part*1024 + h*32+d; lite at 3072+{0,256,512}+h*8+d.
// Writes AD row: [attn_out(1024) | dv(256)].
// =====================================================================
__global__ __launch_bounds__(64)
void attn_kernel(const bf16_t* __restrict__ QKVL, const float* __restrict__ biasH,
                 bf16_t* __restrict__ AD,
                 const float* __restrict__ lam1p, const float* __restrict__ lam2p)
{
    constexpr float SCALE   = 0.17677669529663687f;   // 32^-0.5
    constexpr float SCALE_L = 0.35355339059327373f;   // 8^-0.5
    const int h  = blockIdx.x & 31;
    const int wb = blockIdx.x >> 5;
    const int lane = threadIdx.x;
    __shared__ float Ks[49][32];
    __shared__ float Vs[49][32];
    __shared__ float KLs[49][8];
    __shared__ float VLs[49][8];
    const size_t base = (size_t)wb * 49 * 3840;

    for (int idx = lane; idx < 196; idx += 64) {
        const int r = idx >> 2, s = idx & 3;
        const bf16x8 kv = *(const bf16x8*)(QKVL + base + (size_t)r * 3840 + 1024 + h * 32 + s * 8);
        const bf16x8 vv = *(const bf16x8*)(QKVL + base + (size_t)r * 3840 + 2048 + h * 32 + s * 8);
        #pragma unroll
        for (int e = 0; e < 8; e++) { Ks[r][s * 8 + e] = (float)kv[e]; Vs[r][s * 8 + e] = (float)vv[e]; }
    }
    for (int r = lane; r < 49; r += 64) {
        const bf16x8 kl = *(const bf16x8*)(QKVL + base + (size_t)r * 3840 + 3328 + h * 8);
        const bf16x8 vl = *(const bf16x8*)(QKVL + base + (size_t)r * 3840 + 3584 + h * 8);
        #pragma unroll
        for (int e = 0; e < 8; e++) { KLs[r][e] = (float)kl[e]; VLs[r][e] = (float)vl[e]; }
    }
    __syncthreads();
    const int i = lane;
    if (i >= 49) return;

    float q[32], qlv[8];
    const bf16_t* qp = QKVL + base + (size_t)i * 3840 + h * 32;
    #pragma unroll
    for (int s = 0; s < 4; s++) {
        const bf16x8 t = *(const bf16x8*)(qp + s * 8);
        #pragma unroll
        for (int e = 0; e < 8; e++) q[s * 8 + e] = (float)t[e] * SCALE;
    }
    {
        const bf16x8 t = *(const bf16x8*)(QKVL + base + (size_t)i * 3840 + 3072 + h * 8);
        #pragma unroll
        for (int e = 0; e < 8; e++) qlv[e] = (float)t[e] * SCALE_L;
    }
    const float* bias = biasH + ((size_t)h * 49 + i) * 49;

    float lg[49], lgl[49];
    #pragma unroll
    for (int j = 0; j < 49; j++) {
        float d = 0.f;
        #pragma unroll
        for (int dd = 0; dd < 32; dd++) d += q[dd] * Ks[j][dd];
        lg[j] = d + bias[j];
    }
    #pragma unroll
    for (int j = 0; j < 49; j++) {
        float d = 0.f;
        #pragma unroll
        for (int dd = 0; dd < 8; dd++) d += qlv[dd] * KLs[j][dd];
        lgl[j] = d + bias[j];
    }
    float m1 = -1e30f, m2 = -1e30f;
    #pragma unroll
    for (int j = 0; j < 49; j++) { m1 = fmaxf(m1, lg[j]); m2 = fmaxf(m2, lgl[j]); }
    float s1 = 0.f, s2 = 0.f;
    #pragma unroll
    for (int j = 0; j < 49; j++) {
        lg[j]  = __expf(lg[j]  - m1); s1 += lg[j];
        lgl[j] = __expf(lgl[j] - m2); s2 += lgl[j];
    }
    const float r1 = 1.f / s1, r2 = 1.f / s2;
    const float l1 = 1.f / (1.f + __expf(-*lam1p));
    const float l2 = 1.f / (1.f + __expf(-*lam2p));

    float o[32], ov[8];
    #pragma unroll
    for (int dd = 0; dd < 32; dd++) o[dd] = 0.f;
    #pragma unroll
    for (int dd = 0; dd < 8; dd++) ov[dd] = 0.f;
    #pragma unroll
    for (int j = 0; j < 49; j++) {
        const float a  = lg[j] * r1;
        const float df = l1 * (lgl[j] * r2) - l2 * a;
        #pragma unroll
        for (int dd = 0; dd < 32; dd++) o[dd] += a * Vs[j][dd];
        #pragma unroll
        for (int dd = 0; dd < 8; dd++)  ov[dd] += df * VLs[j][dd];
    }
    bf16_t* orow = AD + ((size_t)wb * 49 + i) * 1280;
    #pragma unroll
    for (int s = 0; s < 4; s++) {
        bf16x8 t;
        #pragma unroll
        for (int e = 0; e < 8; e++) t[e] = (bf16_t)o[s * 8 + e];
        *(bf16x8*)(orow + h * 32 + s * 8) = t;
    }
    {
        bf16x8 t;
        #pragma unroll
        for (int e = 0; e < 8; e++) t[e] = (bf16_t)ov[e];
        *(bf16x8*)(orow + 1024 + h * 8) = t;
    }
}

// =====================================================================
extern "C" void kernel_launch(void* const* d_in, const int* in_sizes, int n_in,
                              void* d_out, int out_size, void* d_ws, size_t ws_size,
                              hipStream_t stream)
{
    const float* x      = (const float*)d_in[0];
    const float* qkv_w  = (const float*)d_in[1];
    const float* qkv_b  = (const float*)d_in[2];
    const float* rpb    = (const float*)d_in[3];
    const int*   rel    = (const int*)d_in[4];
    const float* proj_w = (const float*)d_in[5];
    const float* proj_b = (const float*)d_in[6];
    const float* ql_w   = (const float*)d_in[7];
    const float* kl_w   = (const float*)d_in[8];
    const float* vl_w   = (const float*)d_in[9];
    const float* dp_w   = (const float*)d_in[10];
    const float* dp_b   = (const float*)d_in[11];
    const float* dgamma = (const float*)d_in[12];
    const float* lam1   = (const float*)d_in[13];
    const float* lam2   = (const float*)d_in[14];
    float* out = (float*)d_out;
    (void)in_sizes; (void)n_in; (void)out_size;

    char* p = (char*)d_ws;
    auto alloc = [&](size_t bytes) { char* r = p; p += (bytes + 255) & ~(size_t)255; return r; };
    bf16_t* W1T   = (bf16_t*)alloc((size_t)3840 * 1024 * 2);  // [qkv|ql|kl|vl]^T  (bf16)
    bf16_t* W2T   = (bf16_t*)alloc((size_t)1024 * 1280 * 2);  // [proj^T | g*(dp@proj)^T]
    bf16_t* DPb   = (bf16_t*)alloc((size_t)256 * 1024 * 2);   // dp_w cast to bf16
    bf16_t* Ptmp  = (bf16_t*)alloc((size_t)256 * 1024 * 2);
    float*  biasA = (float*) alloc(3840 * 4);
    float*  biasO = (float*) alloc(1024 * 4);
    float*  biasH = (float*) alloc((size_t)32 * 2401 * 4);
    const size_t fixed = (size_t)(p - (char*)d_ws);
    // largest power-of-2 window chunk that fits: Xb + QKVL + AD = CB*49*6144*2 B
    int CB = 1024;
    while (CB > 1 && fixed + (size_t)CB * 49 * 6144 * 2 + 1024 > ws_size) CB >>= 1;
    bf16_t* Xb   = (bf16_t*)alloc((size_t)CB * 49 * 1024 * 2);
    bf16_t* QKVL = (bf16_t*)alloc((size_t)CB * 49 * 3840 * 2);
    bf16_t* AD   = (bf16_t*)alloc((size_t)CB * 49 * 1280 * 2);

    // ---- prep (fp32 -> bf16 weight transposes, fused-weight build) ----
    transpose_to_bf16<float><<<dim3(32, 96), 256, 0, stream>>>(qkv_w, W1T,                     1024, 3072, 3072, 1024, nullptr);
    transpose_to_bf16<float><<<dim3(32, 8),  256, 0, stream>>>(ql_w,  W1T + (size_t)3072*1024, 1024, 256,  256,  1024, nullptr);
    transpose_to_bf16<float><<<dim3(32, 8),  256, 0, stream>>>(kl_w,  W1T + (size_t)3328*1024, 1024, 256,  256,  1024, nullptr);
    transpose_to_bf16<float><<<dim3(32, 8),  256, 0, stream>>>(vl_w,  W1T + (size_t)3584*1024, 1024, 256,  256,  1024, nullptr);
    transpose_to_bf16<float><<<dim3(32, 32), 256, 0, stream>>>(proj_w, W2T,                    1024, 1024, 1024, 1280, nullptr);
    cast_f32_bf16<<<dim3((256 * 1024 / 4 + 255) / 256), 256, 0, stream>>>(dp_w, DPb, 256 * 1024);
    // Ptmp[j][n] = sum_m dp_w[j][m] * proj_w[m][n]
    gemm_bt<bf16_t><<<dim3(8, 2), 256, 0, stream>>>(DPb, W2T, Ptmp, nullptr, 256, 1024, 1024, 1280, 1024);
    // W2T[n][1024+j] = gamma * Ptmp[j][n]
    transpose_to_bf16<bf16_t><<<dim3(8, 32), 256, 0, stream>>>(Ptmp, W2T + 1024, 256, 1024, 1024, 1280, dgamma);
    prep_biasA<<<dim3(15), 256, 0, stream>>>(qkv_b, biasA);
    prep_biasO<<<dim3(4),  256, 0, stream>>>(proj_b, dp_b, proj_w, dgamma, biasO);
    prep_biasH<<<dim3((32 * 2401 + 255) / 256), 256, 0, stream>>>(rpb, rel, biasH);

    const int nchunk = 1024 / CB;
    const int Mc = CB * 49;
    const int gy = (Mc + 127) / 128;
    for (int cc = 0; cc < nchunk; cc++) {
        const float* xc = x + (size_t)cc * Mc * 1024;
        cast_f32_bf16<<<dim3(((long)Mc * 1024 / 4 + 255) / 256), 256, 0, stream>>>(xc, Xb, (long)Mc * 1024);
        gemm_bt<bf16_t><<<dim3(3840 / 128, gy), 256, 0, stream>>>(
            Xb, W1T, QKVL, biasA, Mc, 1024, 1024, 1024, 3840);
        attn_kernel<<<dim3(CB * 32), 64, 0, stream>>>(QKVL, biasH, AD, lam1, lam2);
        gemm_bt<float><<<dim3(1024 / 128, gy), 256, 0, stream>>>(
            AD, W2T, out + (size_t)cc * Mc * 1024, biasO, Mc, 1280, 1280, 1280, 1024);
    }
}

// Round 4
// 1822.724 us; speedup vs baseline: 1.1072x; 1.1072x over previous
//
#include <hip/hip_runtime.h>
#include <cstdint>
#include <cstddef>

typedef __bf16 bf16_t;
typedef float f32x4 __attribute__((ext_vector_type(4)));
typedef __bf16 bf16x8 __attribute__((ext_vector_type(8)));

// async global->LDS, 16B per lane. LDS dest is wave-uniform base + lane*16B.
#define GLOAD_LDS16(gp, lp)                                                        \
    __builtin_amdgcn_global_load_lds(                                              \
        (const __attribute__((address_space(1))) void*)(gp),                       \
        (__attribute__((address_space(3))) void*)(lp), 16, 0, 0)

// =====================================================================
// GEMM: C[M,N] = A[M,K] @ BT[N,K]^T (+ bias[N]), bf16 in, OutT out, fp32 acc.
// N%256==0, K%64==0; M arbitrary (clamped loads, guarded stores).
// 256x256 tile, 512 thr = 8 waves (2x4), wave tile 128x64 via 8x4
// mfma_16x16x32_bf16. BK=64, double-buffered LDS (128 KB), 1 block/CU.
// LDS fragment-ordered: chunk c (1KB) = (ks=c>>4, tile16=c&15); lane i holds
// row tile*16+(i&15), cols ks*32+(i>>4)*8 -> frag read = base+lane*16B,
// conflict-free b128 (per-lane GLOBAL addr carries the permutation; LDS
// dest linear => global_load_lds-compatible; SQ_LDS_BANK_CONFLICT==0).
// Schedule (T3+T4+T5, counted vmcnt — never drained to 0 mid-loop):
//   prologue: stage t0->buf0, t1->buf1; vmcnt(8); barrier
//   iter t:   compute buf[t&1] (2 ks x {12 ds_read_b128; setprio(1); 32 MFMA});
//             barrier(readers done); stage t+2 -> buf[t&1];
//             vmcnt(8) (tile t+1 landed, t+2 in flight); barrier
// Each tile's 8 DMA loads get a full iteration (~64 MFMA + 24 ds_read) in
// flight -> HBM latency hidden without sacrificing LDS/VGPR to extra TLP.
// =====================================================================
template <typename OutT>
__global__ __launch_bounds__(512, 2)
void gemm_bt(const bf16_t* __restrict__ A, const bf16_t* __restrict__ BT,
             OutT* __restrict__ C, const float* __restrict__ bias,
             int M, int K, int ldA, int ldBT, int ldC)
{
    __shared__ __align__(16) bf16_t As[2][16384];   // 2 x 32 KB
    __shared__ __align__(16) bf16_t Bs[2][16384];   // 2 x 32 KB

    const int bn0 = blockIdx.x * 256;
    const int bm0 = blockIdx.y * 256;
    const int tid  = threadIdx.x;
    const int lane = tid & 63;
    const int w    = tid >> 6;          // wave 0..7
    const int wr   = w >> 2, wc = w & 3;   // 2 x 4 wave grid
    const int lm   = lane & 15, lq = lane >> 4;

    f32x4 acc[8][4];
    #pragma unroll
    for (int i = 0; i < 8; i++)
        #pragma unroll
        for (int j = 0; j < 4; j++) acc[i][j] = (f32x4){0.f, 0.f, 0.f, 0.f};

    // Per-lane global base addresses for this wave's 4 staged chunks of A and
    // B. chunk c = w*4+ci (0..31): ks=c>>4, tile=c&15; lane i -> row
    // tile*16+(i&15), col ks*32+(i>>4)*8. LDS dest &As[buf][c*512]+lane*16B.
    const bf16_t* aptr[4];
    const bf16_t* bptr[4];
    #pragma unroll
    for (int ci = 0; ci < 4; ci++) {
        const int c    = w * 4 + ci;
        const int ks   = c >> 4, tile = c & 15;
        const int col  = ks * 32 + lq * 8;
        int arow = bm0 + tile * 16 + lm;
        if (arow > M - 1) arow = M - 1;       // clamp: garbage compute, no OOB
        aptr[ci] = A  + (size_t)arow * ldA + col;
        bptr[ci] = BT + (size_t)(bn0 + tile * 16 + lm) * ldBT + col;
    }

    const int nt = K >> 6;                    // K-steps of 64

#define STAGE(tt, buf)                                                   \
    {                                                                    \
        const int k0s = (tt) << 6;                                       \
        _Pragma("unroll")                                                \
        for (int ci = 0; ci < 4; ci++) {                                 \
            const int c = w * 4 + ci;                                    \
            GLOAD_LDS16(aptr[ci] + k0s, &As[buf][c * 512]);              \
            GLOAD_LDS16(bptr[ci] + k0s, &Bs[buf][c * 512]);              \
        }                                                                \
    }

    // prologue: 2-deep prefetch
    STAGE(0, 0);
    if (nt > 1) {
        STAGE(1, 1);
        asm volatile("s_waitcnt vmcnt(8)" ::: "memory");  // tile0 landed, tile1 in flight
    } else {
        asm volatile("s_waitcnt vmcnt(0)" ::: "memory");
    }
    __builtin_amdgcn_s_barrier();
    __builtin_amdgcn_sched_barrier(0);

    for (int t = 0; t < nt; ++t) {
        const int cur = t & 1;
        // ---- compute on buf[cur] (tile t: landed + barrier'd) ----
        #pragma unroll
        for (int ks = 0; ks < 2; ks++) {
            bf16x8 af[8], bfv[4];
            #pragma unroll
            for (int t4 = 0; t4 < 8; t4++)
                af[t4] = *(const bf16x8*)&As[cur][(ks * 16 + wr * 8 + t4) * 512 + lane * 8];
            #pragma unroll
            for (int t4 = 0; t4 < 4; t4++)
                bfv[t4] = *(const bf16x8*)&Bs[cur][(ks * 16 + wc * 4 + t4) * 512 + lane * 8];
            __builtin_amdgcn_s_setprio(1);
            #pragma unroll
            for (int mt = 0; mt < 8; mt++)
                #pragma unroll
                for (int nt2 = 0; nt2 < 4; nt2++)
                    acc[mt][nt2] = __builtin_amdgcn_mfma_f32_16x16x32_bf16(
                        af[mt], bfv[nt2], acc[mt][nt2], 0, 0, 0);
            __builtin_amdgcn_s_setprio(0);
        }
        // ---- pipeline tail ----
        if (t + 1 < nt) {
            __builtin_amdgcn_s_barrier();          // all waves done reading buf[cur]
            if (t + 2 < nt) {
                STAGE(t + 2, cur);                 // overwrite buf[cur] with tile t+2
                asm volatile("s_waitcnt vmcnt(8)" ::: "memory");  // tile t+1 landed (mine)
            } else {
                asm volatile("s_waitcnt vmcnt(0)" ::: "memory");  // drain: t+1 landed
            }
            __builtin_amdgcn_s_barrier();          // tile t+1 landed (all waves)
            __builtin_amdgcn_sched_barrier(0);
        }
    }
#undef STAGE

    // epilogue: C/D layout col=lane&15, row=(lane>>4)*4+reg   [m89/m91]
    float bv[4];
    #pragma unroll
    for (int nt2 = 0; nt2 < 4; nt2++)
        bv[nt2] = bias ? bias[bn0 + wc * 64 + nt2 * 16 + lm] : 0.f;
    #pragma unroll
    for (int mt = 0; mt < 8; mt++)
        #pragma unroll
        for (int r2 = 0; r2 < 4; r2++) {
            const int row = bm0 + wr * 128 + mt * 16 + lq * 4 + r2;
            if (row >= M) continue;
            OutT* cp = C + (size_t)row * ldC + bn0 + wc * 64 + lm;
            #pragma unroll
            for (int nt2 = 0; nt2 < 4; nt2++)
                cp[nt2 * 16] = (OutT)(acc[mt][nt2][r2] + bv[nt2]);
        }
}

// =====================================================================
// Tiled transpose + cast: dst[n][k] = scale * src[k][n]; src SrcT, dst bf16.
// =====================================================================
template <typename SrcT>
__global__ void transpose_to_bf16(const SrcT* __restrict__ src, bf16_t* __restrict__ dst,
                                  int K, int N, int ldsrc, int lddst,
                                  const float* __restrict__ scale_ptr)
{
    __shared__ float tile[32][33];
    const int k0 = blockIdx.x * 32, n0 = blockIdx.y * 32;
    const int tx = threadIdx.x & 31, ty = threadIdx.x >> 5;   // 256 thr
    #pragma unroll
    for (int i = 0; i < 4; i++) {
        int k = k0 + ty + 8 * i;
        tile[ty + 8 * i][tx] = (k < K && n0 + tx < N)
            ? (float)src[(size_t)k * ldsrc + n0 + tx] : 0.f;
    }
    __syncthreads();
    const float s = scale_ptr ? *scale_ptr : 1.0f;
    #pragma unroll
    for (int i = 0; i < 4; i++) {
        int n = n0 + ty + 8 * i, k = k0 + tx;
        if (n < N && k < K)
            dst[(size_t)n * lddst + k] = (bf16_t)(s * tile[tx][ty + 8 * i]);
    }
}

// fp32 -> bf16 cast, n % 4 == 0
__global__ void cast_f32_bf16(const float* __restrict__ src, bf16_t* __restrict__ dst, long n)
{
    long i = ((long)blockIdx.x * blockDim.x + threadIdx.x) * 4;
    if (i >= n) return;
    const float4 v = *(const float4*)(src + i);
    bf16_t d0 = (bf16_t)v.x, d1 = (bf16_t)v.y, d2 = (bf16_t)v.z, d3 = (bf16_t)v.w;
    dst[i] = d0; dst[i + 1] = d1; dst[i + 2] = d2; dst[i + 3] = d3;
}

// ---- small prep kernels (all fp32 inputs) ----
__global__ void prep_biasA(const float* __restrict__ qkv_b, float* __restrict__ biasA) {
    int n = blockIdx.x * 256 + threadIdx.x;
    if (n < 3840) biasA[n] = (n < 3072) ? qkv_b[n] : 0.f;
}

__global__ void prep_biasO_init(const float* __restrict__ proj_b, float* __restrict__ biasO) {
    int n = blockIdx.x * 256 + threadIdx.x;
    if (n < 1024) biasO[n] = proj_b[n];
}

// grid (4, 16): 256-wide n block x 64-deep m slice; atomicAdd partials.
__global__ void prep_biasO_acc(const float* __restrict__ dp_b,
                               const float* __restrict__ proj_w,
                               const float* __restrict__ dgamma,
                               float* __restrict__ biasO) {
    const int n  = blockIdx.x * 256 + threadIdx.x;
    const int m0 = blockIdx.y * 64;
    float acc = 0.f;
    #pragma unroll 8
    for (int m = m0; m < m0 + 64; m++) acc += dp_b[m] * proj_w[m * 1024 + n];
    atomicAdd(biasO + n, (*dgamma) * acc);
}

__global__ void prep_biasH(const float* __restrict__ rpb, const int* __restrict__ rel,
                           float* __restrict__ biasH) {
    int t = blockIdx.x * 256 + threadIdx.x;     // t = ij*32 + h
    if (t >= 32 * 49 * 49) return;
    int h = t & 31, ij = t >> 5;
    biasH[(size_t)h * 2401 + ij] = rpb[(size_t)rel[ij] * 32 + h];
}

// =====================================================================
// Attention: one 64-thread block per (window wb, head h).
// QKVL row (3840): [q|k|v] at part*1024 + h*32+d; lite at 3072+{0,256,512}+h*8+d.
// Writes AD row: [attn_out(1024) | dv(256)].
// =====================================================================
__global__ __launch_bounds__(64)
void attn_kernel(const bf16_t* __restrict__ QKVL, const float* __restrict__ biasH,
                 bf16_t* __restrict__ AD,
                 const float* __restrict__ lam1p, const float* __restrict__ lam2p)
{
    constexpr float SCALE   = 0.17677669529663687f;   // 32^-0.5
    constexpr float SCALE_L = 0.35355339059327373f;   // 8^-0.5
    const int h  = blockIdx.x & 31;
    const int wb = blockIdx.x >> 5;
    const int lane = threadIdx.x;
    __shared__ float Ks[49][32];
    __shared__ float Vs[49][32];
    __shared__ float KLs[49][8];
    __shared__ float VLs[49][8];
    const size_t base = (size_t)wb * 49 * 3840;

    for (int idx = lane; idx < 196; idx += 64) {
        const int r = idx >> 2, s = idx & 3;
        const bf16x8 kv = *(const bf16x8*)(QKVL + base + (size_t)r * 3840 + 1024 + h * 32 + s * 8);
        const bf16x8 vv = *(const bf16x8*)(QKVL + base + (size_t)r * 3840 + 2048 + h * 32 + s * 8);
        #pragma unroll
        for (int e = 0; e < 8; e++) { Ks[r][s * 8 + e] = (float)kv[e]; Vs[r][s * 8 + e] = (float)vv[e]; }
    }
    for (int r = lane; r < 49; r += 64) {
        const bf16x8 kl = *(const bf16x8*)(QKVL + base + (size_t)r * 3840 + 3328 + h * 8);
        const bf16x8 vl = *(const bf16x8*)(QKVL + base + (size_t)r * 3840 + 3584 + h * 8);
        #pragma unroll
        for (int e = 0; e < 8; e++) { KLs[r][e] = (float)kl[e]; VLs[r][e] = (float)vl[e]; }
    }
    __syncthreads();
    const int i = lane;
    if (i >= 49) return;

    float q[32], qlv[8];
    const bf16_t* qp = QKVL + base + (size_t)i * 3840 + h * 32;
    #pragma unroll
    for (int s = 0; s < 4; s++) {
        const bf16x8 t = *(const bf16x8*)(qp + s * 8);
        #pragma unroll
        for (int e = 0; e < 8; e++) q[s * 8 + e] = (float)t[e] * SCALE;
    }
    {
        const bf16x8 t = *(const bf16x8*)(QKVL + base + (size_t)i * 3840 + 3072 + h * 8);
        #pragma unroll
        for (int e = 0; e < 8; e++) qlv[e] = (float)t[e] * SCALE_L;
    }
    const float* bias = biasH + ((size_t)h * 49 + i) * 49;

    float lg[49], lgl[49];
    #pragma unroll
    for (int j = 0; j < 49; j++) {
        float d = 0.f;
        #pragma unroll
        for (int dd = 0; dd < 32; dd++) d += q[dd] * Ks[j][dd];
        lg[j] = d + bias[j];
    }
    #pragma unroll
    for (int j = 0; j < 49; j++) {
        float d = 0.f;
        #pragma unroll
        for (int dd = 0; dd < 8; dd++) d += qlv[dd] * KLs[j][dd];
        lgl[j] = d + bias[j];
    }
    float m1 = -1e30f, m2 = -1e30f;
    #pragma unroll
    for (int j = 0; j < 49; j++) { m1 = fmaxf(m1, lg[j]); m2 = fmaxf(m2, lgl[j]); }
    float s1 = 0.f, s2 = 0.f;
    #pragma unroll
    for (int j = 0; j < 49; j++) {
        lg[j]  = __expf(lg[j]  - m1); s1 += lg[j];
        lgl[j] = __expf(lgl[j] - m2); s2 += lgl[j];
    }
    const float r1 = 1.f / s1, r2 = 1.f / s2;
    const float l1 = 1.f / (1.f + __expf(-*lam1p));
    const float l2 = 1.f / (1.f + __expf(-*lam2p));

    float o[32], ov[8];
    #pragma unroll
    for (int dd = 0; dd < 32; dd++) o[dd] = 0.f;
    #pragma unroll
    for (int dd = 0; dd < 8; dd++) ov[dd] = 0.f;
    #pragma unroll
    for (int j = 0; j < 49; j++) {
        const float a  = lg[j] * r1;
        const float df = l1 * (lgl[j] * r2) - l2 * a;
        #pragma unroll
        for (int dd = 0; dd < 32; dd++) o[dd] += a * Vs[j][dd];
        #pragma unroll
        for (int dd = 0; dd < 8; dd++)  ov[dd] += df * VLs[j][dd];
    }
    bf16_t* orow = AD + ((size_t)wb * 49 + i) * 1280;
    #pragma unroll
    for (int s = 0; s < 4; s++) {
        bf16x8 t;
        #pragma unroll
        for (int e = 0; e < 8; e++) t[e] = (bf16_t)o[s * 8 + e];
        *(bf16x8*)(orow + h * 32 + s * 8) = t;
    }
    {
        bf16x8 t;
        #pragma unroll
        for (int e = 0; e < 8; e++) t[e] = (bf16_t)ov[e];
        *(bf16x8*)(orow + 1024 + h * 8) = t;
    }
}

// =====================================================================
extern "C" void kernel_launch(void* const* d_in, const int* in_sizes, int n_in,
                              void* d_out, int out_size, void* d_ws, size_t ws_size,
                              hipStream_t stream)
{
    const float* x      = (const float*)d_in[0];
    const float* qkv_w  = (const float*)d_in[1];
    const float* qkv_b  = (const float*)d_in[2];
    const float* rpb    = (const float*)d_in[3];
    const int*   rel    = (const int*)d_in[4];
    const float* proj_w = (const float*)d_in[5];
    const float* proj_b = (const float*)d_in[6];
    const float* ql_w   = (const float*)d_in[7];
    const float* kl_w   = (const float*)d_in[8];
    const float* vl_w   = (const float*)d_in[9];
    const float* dp_w   = (const float*)d_in[10];
    const float* dp_b   = (const float*)d_in[11];
    const float* dgamma = (const float*)d_in[12];
    const float* lam1   = (const float*)d_in[13];
    const float* lam2   = (const float*)d_in[14];
    float* out = (float*)d_out;
    (void)in_sizes; (void)n_in; (void)out_size;

    char* p = (char*)d_ws;
    auto alloc = [&](size_t bytes) { char* r = p; p += (bytes + 255) & ~(size_t)255; return r; };
    bf16_t* W1T   = (bf16_t*)alloc((size_t)3840 * 1024 * 2);  // [qkv|ql|kl|vl]^T  (bf16)
    bf16_t* W2T   = (bf16_t*)alloc((size_t)1024 * 1280 * 2);  // [proj^T | g*(dp@proj)^T]
    bf16_t* DPb   = (bf16_t*)alloc((size_t)256 * 1024 * 2);   // dp_w cast to bf16
    bf16_t* Ptmp  = (bf16_t*)alloc((size_t)256 * 1024 * 2);
    float*  biasA = (float*) alloc(3840 * 4);
    float*  biasO = (float*) alloc(1024 * 4);
    float*  biasH = (float*) alloc((size_t)32 * 2401 * 4);
    const size_t fixed = (size_t)(p - (char*)d_ws);
    // largest power-of-2 window chunk that fits: Xb + QKVL + AD = CB*49*6144*2 B
    int CB = 1024;
    while (CB > 1 && fixed + (size_t)CB * 49 * 6144 * 2 + 1024 > ws_size) CB >>= 1;
    bf16_t* Xb   = (bf16_t*)alloc((size_t)CB * 49 * 1024 * 2);
    bf16_t* QKVL = (bf16_t*)alloc((size_t)CB * 49 * 3840 * 2);
    bf16_t* AD   = (bf16_t*)alloc((size_t)CB * 49 * 1280 * 2);

    // ---- prep (fp32 -> bf16 weight transposes, fused-weight build) ----
    transpose_to_bf16<float><<<dim3(32, 96), 256, 0, stream>>>(qkv_w, W1T,                     1024, 3072, 3072, 1024, nullptr);
    transpose_to_bf16<float><<<dim3(32, 8),  256, 0, stream>>>(ql_w,  W1T + (size_t)3072*1024, 1024, 256,  256,  1024, nullptr);
    transpose_to_bf16<float><<<dim3(32, 8),  256, 0, stream>>>(kl_w,  W1T + (size_t)3328*1024, 1024, 256,  256,  1024, nullptr);
    transpose_to_bf16<float><<<dim3(32, 8),  256, 0, stream>>>(vl_w,  W1T + (size_t)3584*1024, 1024, 256,  256,  1024, nullptr);
    transpose_to_bf16<float><<<dim3(32, 32), 256, 0, stream>>>(proj_w, W2T,                    1024, 1024, 1024, 1280, nullptr);
    cast_f32_bf16<<<dim3((256 * 1024 / 4 + 255) / 256), 256, 0, stream>>>(dp_w, DPb, 256 * 1024);
    // Ptmp[j][n] = sum_m dp_w[j][m] * proj_w[m][n]
    gemm_bt<bf16_t><<<dim3(4, 1), 512, 0, stream>>>(DPb, W2T, Ptmp, nullptr, 256, 1024, 1024, 1280, 1024);
    // W2T[n][1024+j] = gamma * Ptmp[j][n]
    transpose_to_bf16<bf16_t><<<dim3(8, 32), 256, 0, stream>>>(Ptmp, W2T + 1024, 256, 1024, 1024, 1280, dgamma);
    prep_biasA<<<dim3(15), 256, 0, stream>>>(qkv_b, biasA);
    prep_biasO_init<<<dim3(4), 256, 0, stream>>>(proj_b, biasO);
    prep_biasO_acc<<<dim3(4, 16), 256, 0, stream>>>(dp_b, proj_w, dgamma, biasO);
    prep_biasH<<<dim3((32 * 2401 + 255) / 256), 256, 0, stream>>>(rpb, rel, biasH);

    const int nchunk = 1024 / CB;
    const int Mc = CB * 49;
    const int gy = (Mc + 255) / 256;
    for (int cc = 0; cc < nchunk; cc++) {
        const float* xc = x + (size_t)cc * Mc * 1024;
        cast_f32_bf16<<<dim3(((long)Mc * 1024 / 4 + 255) / 256), 256, 0, stream>>>(xc, Xb, (long)Mc * 1024);
        gemm_bt<bf16_t><<<dim3(3840 / 256, gy), 512, 0, stream>>>(
            Xb, W1T, QKVL, biasA, Mc, 1024, 1024, 1024, 3840);
        attn_kernel<<<dim3(CB * 32), 64, 0, stream>>>(QKVL, biasH, AD, lam1, lam2);
        gemm_bt<float><<<dim3(1024 / 256, gy), 512, 0, stream>>>(
            AD, W2T, out + (size_t)cc * Mc * 1024, biasO, Mc, 1280, 1280, 1280, 1024);
    }
}